// Round 4
// baseline (394.409 us; speedup 1.0000x reference)
//
#include <hip/hip_runtime.h>
#include <math.h>

// Problem constants (match reference)
#define L_IN   131072
#define L_OUT  65536
#define NC     16
#define NB     32
#define KSZ    5

// Tiling: fully-coalesced float4 loads + wave-shuffle halo exchange.
#define THREADS 256
#define CHUNKS  4
#define IN_PER_BLOCK  (THREADS * CHUNKS * 4)   // 4096 inputs/block
#define OUT_PER_BLOCK (IN_PER_BLOCK / 2)       // 2048 outputs/block
#define BPR (L_OUT / OUT_PER_BLOCK)            // 32 blocks per row

// Fast, numerically-stable log_sigmoid(x) = min(x,0) - log(1 + exp(-|x|)).
// (identical math to the round-2 kernel that passed: absmax unchanged)
__device__ __forceinline__ float logsig(float x) {
    float t = __expf(-fabsf(x));
    return fminf(x, 0.0f) - __logf(1.0f + t);
}

// tanh(a) = 1 - 2/(exp(2a)+1): monotone, saturates to +/-1, NaN-free.
__device__ __forceinline__ float fast_tanh(float a) {
    float e = __expf(2.0f * a);
    return 1.0f - __fdividef(2.0f, e + 1.0f);
}

__global__ __launch_bounds__(THREADS) void conv_ls_tanh_kernel(
    const float* __restrict__ x, const float* __restrict__ w,
    const float* __restrict__ bias, float* __restrict__ out)
{
    const int bid  = blockIdx.x;
    const int row  = bid / BPR;                 // b*NC + c
    const int rb   = bid - row * BPR;
    const int c    = row & (NC - 1);
    const int tid  = threadIdx.x;
    const int lane = tid & 63;

    const float* xr   = x   + (size_t)row * L_IN;
    float*       outr = out + (size_t)row * L_OUT;

    const int in_base = rb * IN_PER_BLOCK;      // row-local input index of block

    const float w0 = w[c*KSZ+0], w1 = w[c*KSZ+1], w2 = w[c*KSZ+2],
                w3 = w[c*KSZ+3], w4 = w[c*KSZ+4];
    const float bb = bias[c];

    // ---- Issue all 4 coalesced float4 loads up front (ILP) ----
    // Chunk q: lane-consecutive 16B pieces => one fully-coalesced 1KiB/wave load.
    float4 d[CHUNKS];
    #pragma unroll
    for (int q = 0; q < CHUNKS; ++q) {
        const int gi = in_base + ((q * THREADS + tid) << 2);
        d[q] = *(const float4*)(xr + gi);
    }

    #pragma unroll
    for (int q = 0; q < CHUNKS; ++q) {
        const int gi = in_base + ((q * THREADS + tid) << 2);  // first of 4 inputs

        // logsigmoid exactly once per input element
        const float a0 = logsig(d[q].x);
        const float a1 = logsig(d[q].y);
        const float a2 = logsig(d[q].z);
        const float a3 = logsig(d[q].w);

        // Halo from neighbor lanes: ls[gi-2], ls[gi-1] from lane-1; ls[gi+4] from lane+1.
        float lm2 = __shfl_up(a2, 1);
        float lm1 = __shfl_up(a3, 1);
        float lp4 = __shfl_down(a0, 1);

        // Wave-edge lanes patch halo with clamped (edge-replicate) global loads;
        // these lines were loaded by the neighboring wave -> L1/L2 hits.
        if (lane == 0) {
            lm2 = logsig(xr[max(gi - 2, 0)]);
            lm1 = logsig(xr[max(gi - 1, 0)]);
        }
        if (lane == 63) {
            lp4 = logsig(xr[min(gi + 4, L_IN - 1)]);
        }

        // out[o] = sum_k ls(x[2o-2+k]) * w[k]  (padding=2, stride=2)
        // o0 = gi/2 uses gi-2..gi+2 ; o1 = gi/2+1 uses gi..gi+4
        const float o0 = lm2*w0 + lm1*w1 + a0*w2 + a1*w3 + a2*w4;
        const float o1 = a0*w0  + a1*w1  + a2*w2 + a3*w3 + lp4*w4;

        const int ob = gi >> 1;                 // even => 8B-aligned float2 store
        *(float2*)(outr + ob) = make_float2(fast_tanh(o0 + bb), fast_tanh(o1 + bb));
    }
}

extern "C" void kernel_launch(void* const* d_in, const int* in_sizes, int n_in,
                              void* d_out, int out_size, void* d_ws, size_t ws_size,
                              hipStream_t stream) {
    const float* x    = (const float*)d_in[0];
    const float* w    = (const float*)d_in[1];
    const float* bias = (const float*)d_in[2];
    float* out        = (float*)d_out;

    const int grid = NB * NC * BPR;             // 32*16*32 = 16384 blocks
    conv_ls_tanh_kernel<<<grid, THREADS, 0, stream>>>(x, w, bias, out);
}

// Round 5
// 385.516 us; speedup vs baseline: 1.0231x; 1.0231x over previous
//
#include <hip/hip_runtime.h>
#include <math.h>

// Problem constants (match reference)
#define L_IN   131072
#define L_OUT  65536
#define NC     16
#define NB     32
#define KSZ    5

// Tiling: fully-coalesced float4 loads + wave-shuffle halo exchange.
#define THREADS 256
#define CHUNKS  4
#define IN_PER_BLOCK  (THREADS * CHUNKS * 4)   // 4096 inputs/block
#define OUT_PER_BLOCK (IN_PER_BLOCK / 2)       // 2048 outputs/block
#define BPR (L_OUT / OUT_PER_BLOCK)            // 32 blocks per row

typedef float f32x4 __attribute__((ext_vector_type(4)));
typedef float f32x2 __attribute__((ext_vector_type(2)));

// Fast, numerically-stable log_sigmoid(x) = min(x,0) - log(1 + exp(-|x|)).
// (identical math to rounds 2-4, which passed: absmax 0.0039)
__device__ __forceinline__ float logsig(float x) {
    float t = __expf(-fabsf(x));
    return fminf(x, 0.0f) - __logf(1.0f + t);
}

// tanh(a) = 1 - 2/(exp(2a)+1): monotone, saturates to +/-1, NaN-free.
__device__ __forceinline__ float fast_tanh(float a) {
    float e = __expf(2.0f * a);
    return 1.0f - __fdividef(2.0f, e + 1.0f);
}

__global__ __launch_bounds__(THREADS) void conv_ls_tanh_kernel(
    const float* __restrict__ x, const float* __restrict__ w,
    const float* __restrict__ bias, float* __restrict__ out)
{
    const int bid  = blockIdx.x;
    const int row  = bid / BPR;                 // b*NC + c
    const int rb   = bid - row * BPR;
    const int c    = row & (NC - 1);
    const int tid  = threadIdx.x;
    const int lane = tid & 63;

    const float* xr   = x   + (size_t)row * L_IN;
    float*       outr = out + (size_t)row * L_OUT;

    const int in_base = rb * IN_PER_BLOCK;      // row-local input index of block

    // ---- Issue ALL memory up front so latencies overlap ----
    // Main: chunk q is lane-consecutive 16B pieces => 1KiB/wave coalesced load.
    // Nontemporal: x is stream-once, don't ask caches to retain it.
    f32x4 d[CHUNKS];
    #pragma unroll
    for (int q = 0; q < CHUNKS; ++q) {
        const int gi = in_base + ((q * THREADS + tid) << 2);
        d[q] = __builtin_nontemporal_load((const f32x4*)(xr + gi));
    }

    // Halo patch loads for wave-edge lanes, hoisted OUT of the compute loop:
    // previously issued per-chunk on the critical path (serialized VMEM
    // latencies); now all issue back-to-back with the main loads.
    float pm2[CHUNKS], pm1[CHUNKS], pp4[CHUNKS];
    if (lane == 0) {
        #pragma unroll
        for (int q = 0; q < CHUNKS; ++q) {
            const int gi = in_base + ((q * THREADS + tid) << 2);
            pm2[q] = xr[max(gi - 2, 0)];
            pm1[q] = xr[max(gi - 1, 0)];
        }
    }
    if (lane == 63) {
        #pragma unroll
        for (int q = 0; q < CHUNKS; ++q) {
            const int gi = in_base + ((q * THREADS + tid) << 2);
            pp4[q] = xr[min(gi + 4, L_IN - 1)];
        }
    }

    const float w0 = w[c*KSZ+0], w1 = w[c*KSZ+1], w2 = w[c*KSZ+2],
                w3 = w[c*KSZ+3], w4 = w[c*KSZ+4];
    const float bb = bias[c];

    #pragma unroll
    for (int q = 0; q < CHUNKS; ++q) {
        const int gi = in_base + ((q * THREADS + tid) << 2);  // first of 4 inputs

        // logsigmoid exactly once per input element
        const float a0 = logsig(d[q].x);
        const float a1 = logsig(d[q].y);
        const float a2 = logsig(d[q].z);
        const float a3 = logsig(d[q].w);

        // Halo from neighbor lanes: ls[gi-2], ls[gi-1] from lane-1; ls[gi+4] from lane+1.
        float lm2 = __shfl_up(a2, 1);
        float lm1 = __shfl_up(a3, 1);
        float lp4 = __shfl_down(a0, 1);

        // Wave-edge lanes substitute the prefetched, edge-clamped values.
        if (lane == 0)  { lm2 = logsig(pm2[q]); lm1 = logsig(pm1[q]); }
        if (lane == 63) { lp4 = logsig(pp4[q]); }

        // out[o] = sum_k ls(x[2o-2+k]) * w[k]  (padding=2, stride=2)
        // o0 = gi/2 uses gi-2..gi+2 ; o1 = gi/2+1 uses gi..gi+4
        const float o0 = lm2*w0 + lm1*w1 + a0*w2 + a1*w3 + a2*w4;
        const float o1 = a0*w0  + a1*w1  + a2*w2 + a3*w3 + lp4*w4;

        const int ob = gi >> 1;                 // even => 8B-aligned float2 store
        f32x2 ov; ov.x = fast_tanh(o0 + bb); ov.y = fast_tanh(o1 + bb);
        __builtin_nontemporal_store(ov, (f32x2*)(outr + ob));
    }
}

extern "C" void kernel_launch(void* const* d_in, const int* in_sizes, int n_in,
                              void* d_out, int out_size, void* d_ws, size_t ws_size,
                              hipStream_t stream) {
    const float* x    = (const float*)d_in[0];
    const float* w    = (const float*)d_in[1];
    const float* bias = (const float*)d_in[2];
    float* out        = (float*)d_out;

    const int grid = NB * NC * BPR;             // 32*16*32 = 16384 blocks
    conv_ls_tanh_kernel<<<grid, THREADS, 0, stream>>>(x, w, bias, out);
}